// Round 5
// baseline (6216.847 us; speedup 1.0000x reference)
//
#include <hip/hip_runtime.h>
#include <math.h>
#include <limits.h>

#define H 128
#define V 32000
#define CD 256
#define T_STEPS 21
#define NS 5
#define SOS 1
#define EOS 2
#define B 1024          // unique rows; reference B=5120 is 5 identical copies of each
#define BFULL 5120
#define NCHUNK 250      // V / 128

__device__ __forceinline__ float bf2f(unsigned short u) {
    return __uint_as_float(((unsigned)u) << 16);
}

// np-faithful f32 sigmoid/tanh: f64 interior, single f32 round per np op.
// sigmoid = 1/(1+exp(-x)) with f32 rounds at exp, add, div.
__device__ __forceinline__ float sig32(float x) {
    float t = (float)exp(-(double)x);     // ~np.exp float32 result (<=1ulp)
    float r = __fadd_rn(1.0f, t);
    return __fdiv_rn(1.0f, r);
}
__device__ __forceinline__ float tanh32(float x) { return (float)tanh((double)x); }

// ---------------------------------------------------------------- input dtype sniffer
__global__ void k_detect(const unsigned short* __restrict__ e, int* __restrict__ flag) {
    int i = threadIdx.x;
    unsigned short u = e[2 * i];
    int ex = (u >> 7) & 0xFF;
    bool wild = ((u & 0x7FFF) != 0) && (ex < 0x60 || ex > 0x8F);
    unsigned long long m = __ballot(wild);
    if (i == 0) *flag = (m != 0ull) ? 1 : 0;   // 1 = f32 inputs, 0 = bf16
}

// ---------------------------------------------------------------- transcode input -> f32
__global__ void k_transcode(const void* __restrict__ src, float* __restrict__ dst,
                            int n, const int* __restrict__ flag) {
    int i = blockIdx.x * blockDim.x + threadIdx.x;
    if (i >= n) return;
    if (*flag) dst[i] = ((const float*)src)[i];
    else       dst[i] = bf2f(((const unsigned short*)src)[i]);
}

// ---------------------------------------------------------------- init it/unf
__global__ void k_init_state(int* __restrict__ it, int* __restrict__ unf) {
    int i = blockIdx.x * blockDim.x + threadIdx.x;
    if (i < B) { it[i] = SOS; unf[i] = 1; }
}

// ---------------------------------------------------------------- hc = fl32(x @ W_fc.T) + b_fc  (f32 state out)
__global__ __launch_bounds__(256) void k_init_hc(
    const float* __restrict__ xf, const float* __restrict__ Wfc,
    const float* __restrict__ bfc, float* __restrict__ h, float* __restrict__ c) {
    __shared__ float xl[CD];
    int r = blockIdx.x;
    int j = threadIdx.x;      // 0..255
    xl[j] = xf[(long)r * CD + j];
    __syncthreads();
    const float4* w4 = (const float4*)(Wfc + (long)j * CD);
    double acc = 0.0;
    for (int k4 = 0; k4 < CD / 4; ++k4) {
        float4 w = w4[k4];
        int k = k4 * 4;
        acc += (double)xl[k]     * (double)w.x;
        acc += (double)xl[k + 1] * (double)w.y;
        acc += (double)xl[k + 2] * (double)w.z;
        acc += (double)xl[k + 3] * (double)w.w;
    }
    float hc = __fadd_rn((float)acc, bfc[j]);   // np: gemm result + bias (bias=0)
    if (j < H) h[(long)r * H + j] = hc;
    else       c[(long)r * H + (j - H)] = hc;
}

// ---------------------------------------------------------------- gates (f32 np-faithful):
// g = fl32( fl32(fl32(xt@Wih.T)+bih) + fl32(h@Whh.T) ) + bhh, separate f64 interiors.
__global__ __launch_bounds__(256) void k_gates(
    const void* __restrict__ embed_raw, const float* __restrict__ h,
    const float* __restrict__ Wih, const float* __restrict__ Whh,
    const float* __restrict__ bih, const float* __restrict__ bhh,
    const int* __restrict__ it, float* __restrict__ gates,
    const int* __restrict__ flag) {
    __shared__ float At[16][68];
    __shared__ float Wt[16][68];
    const bool isf = (*flag != 0);
    int tid = threadIdx.x;
    int tx = tid & 15, ty = tid >> 4;
    int rb = blockIdx.x * 64, gb = blockIdx.y * 64;
    int lr = tid >> 2;                 // 0..63
    int lq = (tid & 3) * 4;            // {0,4,8,12}
    int arow = rb + lr;
    int grow = gb + lr;
    int tok = it[arow];
    const float*          erow_f = (const float*)embed_raw + (long)tok * H;
    const unsigned short* erow_h = (const unsigned short*)embed_raw + (long)tok * H;
    const float* hrow = h + (long)arow * H;
    const float* wi   = Wih + (long)grow * H;
    const float* wh   = Whh + (long)grow * H;
    double acc1[4][4] = {};
    double acc2[4][4] = {};
    for (int k0 = 0; k0 < 2 * H; k0 += 16) {
        int k = k0 + lq;
        float v0, v1, v2, v3;
        if (k < H) {
            if (isf) {
                float4 f = *(const float4*)(erow_f + k);
                v0 = f.x; v1 = f.y; v2 = f.z; v3 = f.w;
            } else {
                ushort4 u = *(const ushort4*)(erow_h + k);
                v0 = bf2f(u.x); v1 = bf2f(u.y); v2 = bf2f(u.z); v3 = bf2f(u.w);
            }
        } else {
            float4 f = *(const float4*)(hrow + (k - H));
            v0 = f.x; v1 = f.y; v2 = f.z; v3 = f.w;
        }
        At[lq + 0][lr] = v0; At[lq + 1][lr] = v1; At[lq + 2][lr] = v2; At[lq + 3][lr] = v3;
        float4 g;
        if (k < H) g = *(const float4*)(wi + k);
        else       g = *(const float4*)(wh + (k - H));
        Wt[lq + 0][lr] = g.x; Wt[lq + 1][lr] = g.y; Wt[lq + 2][lr] = g.z; Wt[lq + 3][lr] = g.w;
        __syncthreads();
        if (k0 < H) {
            #pragma unroll
            for (int kk = 0; kk < 16; ++kk) {
                float a[4], w[4];
                #pragma unroll
                for (int i = 0; i < 4; ++i) a[i] = At[kk][ty * 4 + i];
                #pragma unroll
                for (int j = 0; j < 4; ++j) w[j] = Wt[kk][tx * 4 + j];
                #pragma unroll
                for (int i = 0; i < 4; ++i)
                    #pragma unroll
                    for (int j = 0; j < 4; ++j)
                        acc1[i][j] += (double)a[i] * (double)w[j];
            }
        } else {
            #pragma unroll
            for (int kk = 0; kk < 16; ++kk) {
                float a[4], w[4];
                #pragma unroll
                for (int i = 0; i < 4; ++i) a[i] = At[kk][ty * 4 + i];
                #pragma unroll
                for (int j = 0; j < 4; ++j) w[j] = Wt[kk][tx * 4 + j];
                #pragma unroll
                for (int i = 0; i < 4; ++i)
                    #pragma unroll
                    for (int j = 0; j < 4; ++j)
                        acc2[i][j] += (double)a[i] * (double)w[j];
            }
        }
        __syncthreads();
    }
    #pragma unroll
    for (int i = 0; i < 4; ++i) {
        long row = rb + ty * 4 + i;
        #pragma unroll
        for (int j = 0; j < 4; ++j) {
            int g = gb + tx * 4 + j;
            float t = __fadd_rn((float)acc1[i][j], bih[g]);   // xt@Wih.T + bih
            t = __fadd_rn(t, (float)acc2[i][j]);              // + h@Whh.T
            t = __fadd_rn(t, bhh[g]);                         // + bhh
            gates[row * (4 * H) + g] = t;
        }
    }
}

// ---------------------------------------------------------------- LSTM cell (f32 np-op-faithful) + p = fl32(h@W1.T)+b1
__global__ __launch_bounds__(256) void k_cell_proj(
    const float* __restrict__ gates, float* __restrict__ h, float* __restrict__ c,
    const float* __restrict__ W1, const float* __restrict__ b1,
    float* __restrict__ p32) {
    __shared__ float hl[8][132];
    int tid = threadIdx.x;
    int rb = blockIdx.x * 8;
    #pragma unroll
    for (int i = 0; i < 4; ++i) {
        int lin = tid + i * 256;
        int lr = lin >> 7, j = lin & 127;
        long row = rb + lr;
        const float* g = gates + row * 512;
        float gi = g[j], gf = g[j + 128], gg = g[j + 256], go = g[j + 384];
        float cv = c[row * 128 + j];
        float si = sig32(gi);
        float sf = sig32(gf);
        float so = sig32(go);
        float tg = tanh32(gg);
        float cn = __fadd_rn(__fmul_rn(sf, cv), __fmul_rn(si, tg));
        float hn = __fmul_rn(so, tanh32(cn));
        c[row * 128 + j] = cn;
        h[row * 128 + j] = hn;
        hl[lr][j] = hn;
    }
    __syncthreads();
    int j = tid & 127;
    int rbase = (tid >> 7) * 4;
    const float4* w4 = (const float4*)(W1 + (long)j * H);
    double acc[4] = {};
    for (int k4 = 0; k4 < H / 4; ++k4) {
        float4 w = w4[k4];
        int k = k4 * 4;
        #pragma unroll
        for (int rr = 0; rr < 4; ++rr) {
            acc[rr] += (double)hl[rbase + rr][k]     * (double)w.x;
            acc[rr] += (double)hl[rbase + rr][k + 1] * (double)w.y;
            acc[rr] += (double)hl[rbase + rr][k + 2] * (double)w.z;
            acc[rr] += (double)hl[rbase + rr][k + 3] * (double)w.w;
        }
    }
    #pragma unroll
    for (int rr = 0; rr < 4; ++rr) {
        long row = rb + rbase + rr;
        p32[row * H + j] = __fadd_rn((float)acc[rr], b1[j]);
    }
}

// ---------------------------------------------------------------- vocab tiles: 64 rows x 128 vocab (2 subtiles of 64).
// logit l = fl32(f64dot(p, W2row)) + b2 (f32 round) — k ascending order (rescan replicates bit-exactly).
// Emits per-(row,chunk): f32 max logit, f64 sum exp64(l) (unshifted; l bounded).
__global__ __launch_bounds__(256) void k_vchunk(
    const float* __restrict__ p32, const void* __restrict__ W2_raw,
    const float* __restrict__ b2, float* __restrict__ cm,
    double* __restrict__ cs, const int* __restrict__ flag) {
    __shared__ float At[16][68];
    __shared__ float Wt[16][68];
    const bool isf = (*flag != 0);
    int tid = threadIdx.x;
    int tx = tid & 15, ty = tid >> 4;
    int rb = blockIdx.x * 64;
    int cb = blockIdx.y;              // 0..249
    int lr = tid >> 2;                // 0..63
    int lq = (tid & 3) * 4;           // {0,4,8,12}
    const float* arow = p32 + (long)(rb + lr) * H;

    float bestv[4]; double ssum[4];
    #pragma unroll
    for (int i = 0; i < 4; ++i) { bestv[i] = -__builtin_inff(); ssum[i] = 0.0; }

    for (int sub = 0; sub < 2; ++sub) {
        int vb = cb * 128 + sub * 64;
        const float*          wrow_f = (const float*)W2_raw + (long)(vb + lr) * H;
        const unsigned short* wrow_h = (const unsigned short*)W2_raw + (long)(vb + lr) * H;
        double acc[4][4] = {};
        for (int k0 = 0; k0 < H; k0 += 16) {
            int k = k0 + lq;
            float4 a = *(const float4*)(arow + k);
            At[lq + 0][lr] = a.x; At[lq + 1][lr] = a.y;
            At[lq + 2][lr] = a.z; At[lq + 3][lr] = a.w;
            if (isf) {
                float4 g = *(const float4*)(wrow_f + k);
                Wt[lq + 0][lr] = g.x; Wt[lq + 1][lr] = g.y;
                Wt[lq + 2][lr] = g.z; Wt[lq + 3][lr] = g.w;
            } else {
                ushort4 u = *(const ushort4*)(wrow_h + k);
                Wt[lq + 0][lr] = bf2f(u.x); Wt[lq + 1][lr] = bf2f(u.y);
                Wt[lq + 2][lr] = bf2f(u.z); Wt[lq + 3][lr] = bf2f(u.w);
            }
            __syncthreads();
            #pragma unroll
            for (int kk = 0; kk < 16; ++kk) {
                float a2[4], w2[4];
                #pragma unroll
                for (int i = 0; i < 4; ++i) a2[i] = At[kk][ty * 4 + i];
                #pragma unroll
                for (int j = 0; j < 4; ++j) w2[j] = Wt[kk][tx * 4 + j];
                #pragma unroll
                for (int i = 0; i < 4; ++i)
                    #pragma unroll
                    for (int j = 0; j < 4; ++j)
                        acc[i][j] += (double)a2[i] * (double)w2[j];
            }
            __syncthreads();
        }
        #pragma unroll
        for (int i = 0; i < 4; ++i) {
            #pragma unroll
            for (int j = 0; j < 4; ++j) {
                int v = vb + tx * 4 + j;
                float l = __fadd_rn((float)acc[i][j], b2[v]);
                ssum[i] += exp((double)l);
                bestv[i] = fmaxf(bestv[i], l);
            }
        }
    }
    #pragma unroll
    for (int i = 0; i < 4; ++i) {
        float bv = bestv[i]; double s = ssum[i];
        #pragma unroll
        for (int off = 1; off < 16; off <<= 1) {
            bv = fmaxf(bv, __shfl_xor(bv, off, 64));
            s += __shfl_xor(s, off, 64);
        }
        if (tx == 0) {
            long row = rb + ty * 4 + i;
            cm[row * NCHUNK + cb] = bv;
            cs[row * NCHUNK + cb] = s;
        }
    }
}

// ---------------------------------------------------------------- finalize: M, L, np-exact logprob argmax via rescan
__global__ __launch_bounds__(64) void k_final(
    const float* __restrict__ cm, const double* __restrict__ cs,
    const float* __restrict__ p32, const void* __restrict__ W2_raw,
    const float* __restrict__ b2, int* __restrict__ it, int* __restrict__ unf,
    float* __restrict__ out, int t, const int* __restrict__ flag) {
    const bool isf = (*flag != 0);
    int r = blockIdx.x;
    int lane = threadIdx.x;
    const float*  cmr = cm + (long)r * NCHUNK;
    const double* csr = cs + (long)r * NCHUNK;
    float marr[4];
    float M = -__builtin_inff();
    #pragma unroll
    for (int i = 0; i < 4; ++i) {
        int cc = lane + 64 * i;
        marr[i] = (cc < NCHUNK) ? cmr[cc] : -__builtin_inff();
        M = fmaxf(M, marr[i]);
    }
    #pragma unroll
    for (int off = 1; off < 64; off <<= 1) M = fmaxf(M, __shfl_xor(M, off, 64));
    double S = 0.0;
    #pragma unroll
    for (int i = 0; i < 4; ++i) {
        int cc = lane + 64 * i;
        if (cc < NCHUNK) S += csr[cc];
    }
    #pragma unroll
    for (int off = 1; off < 64; off <<= 1) S += __shfl_xor(S, off, 64);
    // np: L = fl32(log(sum(exp(l - M)))). Unshifted f64 interior: log(S) - M.
    float L = (float)(log(S) - (double)M);
    float negL = __fsub_rn(0.0f, L);     // exact negation; == max logprob value

    // np.argmax(logprobs): first v with fl32(fl32(l - M) - L) == -L.
    const float* pr = p32 + (long)r * H;
    int best = INT_MAX;
    for (int i = 0; i < 4 && best == INT_MAX; ++i) {
        unsigned long long mask = __ballot(marr[i] >= M - 1e-4f);
        while (mask && best == INT_MAX) {
            int b = __ffsll(mask) - 1;
            mask &= mask - 1;
            int cc = i * 64 + b;              // ascending chunk order
            int hit = INT_MAX;
            #pragma unroll
            for (int q = 0; q < 2; ++q) {
                int v = cc * 128 + q * 64 + lane;
                // bit-identical replication of k_vchunk's dot: f64 acc, k ascending
                double acc = 0.0;
                if (isf) {
                    const float* wv = (const float*)W2_raw + (long)v * H;
                    for (int k = 0; k < H; ++k) acc += (double)pr[k] * (double)wv[k];
                } else {
                    const unsigned short* wv = (const unsigned short*)W2_raw + (long)v * H;
                    for (int k = 0; k < H; ++k) acc += (double)pr[k] * (double)bf2f(wv[k]);
                }
                float l  = __fadd_rn((float)acc, b2[v]);
                float lp = __fsub_rn(__fsub_rn(l, M), L);
                if (lp == negL && v < hit) hit = v;
            }
            #pragma unroll
            for (int off = 1; off < 64; off <<= 1) {
                int oh = __shfl_xor(hit, off, 64);
                hit = (oh < hit) ? oh : hit;
            }
            if (hit != INT_MAX) best = hit;   // wave-uniform
        }
    }
    int bi = (best == INT_MAX) ? 0 : best;    // guaranteed found (M's chunk qualifies)

    int unfr = unf[r];
    float lp = negL;                          // logprob at argmax == -L by construction
    int itn = unfr ? bi : 0;
    int unfn = (unfr && itn != EOS) ? 1 : 0;
    if (lane == 0) { it[r] = itn; unf[r] = unfn; }
    if (lane < NS) {
        long ro = (long)r * NS + lane;        // the 5 identical output copies
        out[ro * T_STEPS + t] = (float)itn;
        out[(long)BFULL * T_STEPS + ro * T_STEPS + t] = lp;
        out[2L * BFULL * T_STEPS + ro * T_STEPS + t] = unfr ? 1.0f : 0.0f;
    }
}

// ---------------------------------------------------------------- launch
extern "C" void kernel_launch(void* const* d_in, const int* in_sizes, int n_in,
                              void* d_out, int out_size, void* d_ws, size_t ws_size,
                              hipStream_t stream) {
    float* out = (float*)d_out;

    char* w = (char*)d_ws;
    float* fin[12];
    for (int i = 0; i < 12; ++i) {
        if (i == 1 || i == 10) { fin[i] = nullptr; continue; }   // embed/W2 read raw
        fin[i] = (float*)w;
        size_t bytes = ((size_t)in_sizes[i] * 4 + 15) & ~(size_t)15;
        w += bytes;
    }
    float*  h     = (float*) w; w += (size_t)B * H * 4;
    float*  c     = (float*) w; w += (size_t)B * H * 4;
    float*  gates = (float*) w; w += (size_t)B * 4 * H * 4;
    float*  p32   = (float*) w; w += (size_t)B * H * 4;
    float*  cm    = (float*) w; w += (size_t)B * NCHUNK * 4;
    double* cs    = (double*)w; w += (size_t)B * NCHUNK * 8;
    int*    it    = (int*)   w; w += (size_t)B * 4;
    int*    unf   = (int*)   w; w += (size_t)B * 4;
    int*    flag  = (int*)   w; w += 16;

    k_detect<<<1, 64, 0, stream>>>((const unsigned short*)d_in[1], flag);
    for (int i = 0; i < 12; ++i) {
        if (i == 1 || i == 10) continue;
        int n = in_sizes[i];
        k_transcode<<<(n + 255) / 256, 256, 0, stream>>>(d_in[i], fin[i], n, flag);
    }

    const float* xf  = fin[0];
    const float* Wfc = fin[2];
    const float* bfc = fin[3];
    const float* Wih = fin[4];
    const float* bih = fin[5];
    const float* Whh = fin[6];
    const float* bhh = fin[7];
    const float* W1  = fin[8];
    const float* b1  = fin[9];
    const float* b2  = fin[11];

    k_init_state<<<(B + 255) / 256, 256, 0, stream>>>(it, unf);
    k_init_hc<<<B, 256, 0, stream>>>(xf, Wfc, bfc, h, c);
    for (int t = 0; t < T_STEPS; ++t) {
        k_gates<<<dim3(B / 64, 8), 256, 0, stream>>>(d_in[1], h, Wih, Whh, bih, bhh, it, gates, flag);
        k_cell_proj<<<B / 8, 256, 0, stream>>>(gates, h, c, W1, b1, p32);
        k_vchunk<<<dim3(B / 64, NCHUNK), 256, 0, stream>>>(p32, d_in[10], b2, cm, cs, flag);
        k_final<<<B, 64, 0, stream>>>(cm, cs, p32, d_in[10], b2, it, unf, out, t, flag);
    }
}

// Round 9
// 5206.762 us; speedup vs baseline: 1.1940x; 1.1940x over previous
//
#include <hip/hip_runtime.h>
#include <math.h>
#include <limits.h>

#define H 128
#define V 32000
#define CD 256
#define T_STEPS 21
#define NS 5
#define SOS 1
#define EOS 2
#define B 1024          // unique rows; reference B=5120 is 5 identical copies of each
#define BFULL 5120
#define NCHUNK 250      // V / 128

__device__ __forceinline__ float bf2f(unsigned short u) {
    return __uint_as_float(((unsigned)u) << 16);
}

// np-faithful f32 sigmoid/tanh: f64 interior, single f32 round per np op.
__device__ __forceinline__ float sig32(float x) {
    float t = (float)exp(-(double)x);
    float r = __fadd_rn(1.0f, t);
    return __fdiv_rn(1.0f, r);
}
__device__ __forceinline__ float tanh32(float x) { return (float)tanh((double)x); }

// ---------------------------------------------------------------- input dtype sniffer
__global__ void k_detect(const unsigned short* __restrict__ e, int* __restrict__ flag) {
    int i = threadIdx.x;
    unsigned short u = e[2 * i];
    int ex = (u >> 7) & 0xFF;
    bool wild = ((u & 0x7FFF) != 0) && (ex < 0x60 || ex > 0x8F);
    unsigned long long m = __ballot(wild);
    if (i == 0) *flag = (m != 0ull) ? 1 : 0;   // 1 = f32 inputs, 0 = bf16
}

// ---------------------------------------------------------------- transcode input -> f32
__global__ void k_transcode(const void* __restrict__ src, float* __restrict__ dst,
                            int n, const int* __restrict__ flag) {
    int i = blockIdx.x * blockDim.x + threadIdx.x;
    if (i >= n) return;
    if (*flag) dst[i] = ((const float*)src)[i];
    else       dst[i] = bf2f(((const unsigned short*)src)[i]);
}

// ---------------------------------------------------------------- init it/unf
__global__ void k_init_state(int* __restrict__ it, int* __restrict__ unf) {
    int i = blockIdx.x * blockDim.x + threadIdx.x;
    if (i < B) { it[i] = SOS; unf[i] = 1; }
}

// ---------------------------------------------------------------- hc = fl32(x @ W_fc.T) + b_fc
__global__ __launch_bounds__(256) void k_init_hc(
    const float* __restrict__ xf, const float* __restrict__ Wfc,
    const float* __restrict__ bfc, float* __restrict__ h, float* __restrict__ c) {
    __shared__ float xl[CD];
    int r = blockIdx.x;
    int j = threadIdx.x;
    xl[j] = xf[(long)r * CD + j];
    __syncthreads();
    const float4* w4 = (const float4*)(Wfc + (long)j * CD);
    double acc = 0.0;
    for (int k4 = 0; k4 < CD / 4; ++k4) {
        float4 w = w4[k4];
        int k = k4 * 4;
        acc += (double)xl[k]     * (double)w.x;
        acc += (double)xl[k + 1] * (double)w.y;
        acc += (double)xl[k + 2] * (double)w.z;
        acc += (double)xl[k + 3] * (double)w.w;
    }
    float hc = __fadd_rn((float)acc, bfc[j]);
    if (j < H) h[(long)r * H + j] = hc;
    else       c[(long)r * H + (j - H)] = hc;
}

// ---------------------------------------------------------------- gates (f32 np-faithful) — r5 verbatim
__global__ __launch_bounds__(256) void k_gates(
    const void* __restrict__ embed_raw, const float* __restrict__ h,
    const float* __restrict__ Wih, const float* __restrict__ Whh,
    const float* __restrict__ bih, const float* __restrict__ bhh,
    const int* __restrict__ it, float* __restrict__ gates,
    const int* __restrict__ flag) {
    __shared__ float At[16][68];
    __shared__ float Wt[16][68];
    const bool isf = (*flag != 0);
    int tid = threadIdx.x;
    int tx = tid & 15, ty = tid >> 4;
    int rb = blockIdx.x * 64, gb = blockIdx.y * 64;
    int lr = tid >> 2;
    int lq = (tid & 3) * 4;
    int arow = rb + lr;
    int grow = gb + lr;
    int tok = it[arow];
    const float*          erow_f = (const float*)embed_raw + (long)tok * H;
    const unsigned short* erow_h = (const unsigned short*)embed_raw + (long)tok * H;
    const float* hrow = h + (long)arow * H;
    const float* wi   = Wih + (long)grow * H;
    const float* wh   = Whh + (long)grow * H;
    double acc1[4][4] = {};
    double acc2[4][4] = {};
    for (int k0 = 0; k0 < 2 * H; k0 += 16) {
        int k = k0 + lq;
        float v0, v1, v2, v3;
        if (k < H) {
            if (isf) {
                float4 f = *(const float4*)(erow_f + k);
                v0 = f.x; v1 = f.y; v2 = f.z; v3 = f.w;
            } else {
                ushort4 u = *(const ushort4*)(erow_h + k);
                v0 = bf2f(u.x); v1 = bf2f(u.y); v2 = bf2f(u.z); v3 = bf2f(u.w);
            }
        } else {
            float4 f = *(const float4*)(hrow + (k - H));
            v0 = f.x; v1 = f.y; v2 = f.z; v3 = f.w;
        }
        At[lq + 0][lr] = v0; At[lq + 1][lr] = v1; At[lq + 2][lr] = v2; At[lq + 3][lr] = v3;
        float4 g;
        if (k < H) g = *(const float4*)(wi + k);
        else       g = *(const float4*)(wh + (k - H));
        Wt[lq + 0][lr] = g.x; Wt[lq + 1][lr] = g.y; Wt[lq + 2][lr] = g.z; Wt[lq + 3][lr] = g.w;
        __syncthreads();
        if (k0 < H) {
            #pragma unroll
            for (int kk = 0; kk < 16; ++kk) {
                float a[4], w[4];
                #pragma unroll
                for (int i = 0; i < 4; ++i) a[i] = At[kk][ty * 4 + i];
                #pragma unroll
                for (int j = 0; j < 4; ++j) w[j] = Wt[kk][tx * 4 + j];
                #pragma unroll
                for (int i = 0; i < 4; ++i)
                    #pragma unroll
                    for (int j = 0; j < 4; ++j)
                        acc1[i][j] += (double)a[i] * (double)w[j];
            }
        } else {
            #pragma unroll
            for (int kk = 0; kk < 16; ++kk) {
                float a[4], w[4];
                #pragma unroll
                for (int i = 0; i < 4; ++i) a[i] = At[kk][ty * 4 + i];
                #pragma unroll
                for (int j = 0; j < 4; ++j) w[j] = Wt[kk][tx * 4 + j];
                #pragma unroll
                for (int i = 0; i < 4; ++i)
                    #pragma unroll
                    for (int j = 0; j < 4; ++j)
                        acc2[i][j] += (double)a[i] * (double)w[j];
            }
        }
        __syncthreads();
    }
    #pragma unroll
    for (int i = 0; i < 4; ++i) {
        long row = rb + ty * 4 + i;
        #pragma unroll
        for (int j = 0; j < 4; ++j) {
            int g = gb + tx * 4 + j;
            float t = __fadd_rn((float)acc1[i][j], bih[g]);
            t = __fadd_rn(t, (float)acc2[i][j]);
            t = __fadd_rn(t, bhh[g]);
            gates[row * (4 * H) + g] = t;
        }
    }
}

// ---------------------------------------------------------------- LSTM cell + p-projection — r5 verbatim
__global__ __launch_bounds__(256) void k_cell_proj(
    const float* __restrict__ gates, float* __restrict__ h, float* __restrict__ c,
    const float* __restrict__ W1, const float* __restrict__ b1,
    float* __restrict__ p32) {
    __shared__ float hl[8][132];
    int tid = threadIdx.x;
    int rb = blockIdx.x * 8;
    #pragma unroll
    for (int i = 0; i < 4; ++i) {
        int lin = tid + i * 256;
        int lr = lin >> 7, j = lin & 127;
        long row = rb + lr;
        const float* g = gates + row * 512;
        float gi = g[j], gf = g[j + 128], gg = g[j + 256], go = g[j + 384];
        float cv = c[row * 128 + j];
        float si = sig32(gi);
        float sf = sig32(gf);
        float so = sig32(go);
        float tg = tanh32(gg);
        float cn = __fadd_rn(__fmul_rn(sf, cv), __fmul_rn(si, tg));
        float hn = __fmul_rn(so, tanh32(cn));
        c[row * 128 + j] = cn;
        h[row * 128 + j] = hn;
        hl[lr][j] = hn;
    }
    __syncthreads();
    int j = tid & 127;
    int rbase = (tid >> 7) * 4;
    const float4* w4 = (const float4*)(W1 + (long)j * H);
    double acc[4] = {};
    for (int k4 = 0; k4 < H / 4; ++k4) {
        float4 w = w4[k4];
        int k = k4 * 4;
        #pragma unroll
        for (int rr = 0; rr < 4; ++rr) {
            acc[rr] += (double)hl[rbase + rr][k]     * (double)w.x;
            acc[rr] += (double)hl[rbase + rr][k + 1] * (double)w.y;
            acc[rr] += (double)hl[rbase + rr][k + 2] * (double)w.z;
            acc[rr] += (double)hl[rbase + rr][k + 3] * (double)w.w;
        }
    }
    #pragma unroll
    for (int rr = 0; rr < 4; ++rr) {
        long row = rb + rbase + rr;
        p32[row * H + j] = __fadd_rn((float)acc[rr], b1[j]);
    }
}

// ---------------------------------------------------------------- EXACT vocab tile, optimized:
// 128 rows x 128 cols per block, 256 threads, 8x8 f64 acc each, f32 LDS staging.
// Recipe bit-identical to r5/k_final: f64 dot with ascending k, l = fl32(acc)+b2.
// cs = f32 sum of __expf(l) (L tolerance ~1e-2 after bf16-quantized compare).
__global__ __launch_bounds__(256, 2) void k_vchunk(
    const float* __restrict__ p32, const void* __restrict__ W2_raw,
    const float* __restrict__ b2, float* __restrict__ cm,
    float* __restrict__ cs, const int* __restrict__ flag) {
    __shared__ float At[16][132];
    __shared__ float Wt[16][132];
    const bool isf = (*flag != 0);
    int tid = threadIdx.x;
    int tx = tid & 15, ty = tid >> 4;
    int rb = blockIdx.x * 128;
    int cb = blockIdx.y;
    int vb = cb * 128;
    double acc[8][8] = {};
    for (int k0 = 0; k0 < H; k0 += 16) {
        // stage A (128 rows x 16 k) and W (128 cols x 16 k), 2 float4 slots/thread each
        #pragma unroll
        for (int i = 0; i < 2; ++i) {
            int lin = tid + i * 256;           // 0..511
            int row = lin >> 2, kq = (lin & 3) * 4;
            float4 a = *(const float4*)(p32 + (long)(rb + row) * H + k0 + kq);
            At[kq + 0][row] = a.x; At[kq + 1][row] = a.y;
            At[kq + 2][row] = a.z; At[kq + 3][row] = a.w;
            if (isf) {
                float4 g = *(const float4*)((const float*)W2_raw + (long)(vb + row) * H + k0 + kq);
                Wt[kq + 0][row] = g.x; Wt[kq + 1][row] = g.y;
                Wt[kq + 2][row] = g.z; Wt[kq + 3][row] = g.w;
            } else {
                ushort4 u = *(const ushort4*)((const unsigned short*)W2_raw + (long)(vb + row) * H + k0 + kq);
                Wt[kq + 0][row] = bf2f(u.x); Wt[kq + 1][row] = bf2f(u.y);
                Wt[kq + 2][row] = bf2f(u.z); Wt[kq + 3][row] = bf2f(u.w);
            }
        }
        __syncthreads();
        #pragma unroll
        for (int kk = 0; kk < 16; ++kk) {
            double a8[8], w8[8];
            #pragma unroll
            for (int i = 0; i < 8; ++i) a8[i] = (double)At[kk][ty * 8 + i];
            #pragma unroll
            for (int j = 0; j < 8; ++j) w8[j] = (double)Wt[kk][tx * 8 + j];
            #pragma unroll
            for (int i = 0; i < 8; ++i)
                #pragma unroll
                for (int j = 0; j < 8; ++j)
                    acc[i][j] += a8[i] * w8[j];
        }
        __syncthreads();
    }
    // epilogue: exact per-row chunk max + f32 expf sum, reduce over 16 tx lanes
    float bb[8];
    #pragma unroll
    for (int j = 0; j < 8; ++j) bb[j] = b2[vb + tx * 8 + j];
    #pragma unroll
    for (int i = 0; i < 8; ++i) {
        float mx = -__builtin_inff();
        float s = 0.f;
        #pragma unroll
        for (int j = 0; j < 8; ++j) {
            float l = __fadd_rn((float)acc[i][j], bb[j]);
            mx = fmaxf(mx, l);
            s += __expf(l);
        }
        #pragma unroll
        for (int off = 1; off < 16; off <<= 1) {
            mx = fmaxf(mx, __shfl_xor(mx, off, 64));
            s += __shfl_xor(s, off, 64);
        }
        if (tx == 0) {
            long row = rb + ty * 8 + i;
            cm[row * NCHUNK + cb] = mx;
            cs[row * NCHUNK + cb] = s;
        }
    }
}

// ---------------------------------------------------------------- finalize — r5 verbatim (cs now f32)
__global__ __launch_bounds__(64) void k_final(
    const float* __restrict__ cm, const float* __restrict__ cs,
    const float* __restrict__ p32, const void* __restrict__ W2_raw,
    const float* __restrict__ b2, int* __restrict__ it, int* __restrict__ unf,
    float* __restrict__ out, int t, const int* __restrict__ flag) {
    const bool isf = (*flag != 0);
    int r = blockIdx.x;
    int lane = threadIdx.x;
    const float* cmr = cm + (long)r * NCHUNK;
    const float* csr = cs + (long)r * NCHUNK;
    float marr[4];
    float M = -__builtin_inff();
    #pragma unroll
    for (int i = 0; i < 4; ++i) {
        int cc = lane + 64 * i;
        marr[i] = (cc < NCHUNK) ? cmr[cc] : -__builtin_inff();
        M = fmaxf(M, marr[i]);
    }
    #pragma unroll
    for (int off = 1; off < 64; off <<= 1) M = fmaxf(M, __shfl_xor(M, off, 64));
    double S = 0.0;
    #pragma unroll
    for (int i = 0; i < 4; ++i) {
        int cc = lane + 64 * i;
        if (cc < NCHUNK) S += (double)csr[cc];
    }
    #pragma unroll
    for (int off = 1; off < 64; off <<= 1) S += __shfl_xor(S, off, 64);
    float L = (float)(log(S) - (double)M);
    float negL = __fsub_rn(0.0f, L);

    // np.argmax(logprobs): first v with fl32(fl32(l - M) - L) == -L (cm exact).
    const float* pr = p32 + (long)r * H;
    int best = INT_MAX;
    #pragma unroll 1
    for (int i = 0; i < 4 && best == INT_MAX; ++i) {
        unsigned long long mask = __ballot(marr[i] >= M - 1e-4f);
        while (mask && best == INT_MAX) {
            int b = __ffsll(mask) - 1;
            mask &= mask - 1;
            int cc = i * 64 + b;
            int hit = INT_MAX;
            #pragma unroll
            for (int q = 0; q < 2; ++q) {
                int v = cc * 128 + q * 64 + lane;
                double acc = 0.0;
                if (isf) {
                    const float* wv = (const float*)W2_raw + (long)v * H;
                    for (int k = 0; k < H; ++k) acc += (double)pr[k] * (double)wv[k];
                } else {
                    const unsigned short* wv = (const unsigned short*)W2_raw + (long)v * H;
                    for (int k = 0; k < H; ++k) acc += (double)pr[k] * (double)bf2f(wv[k]);
                }
                float l  = __fadd_rn((float)acc, b2[v]);
                float lp = __fsub_rn(__fsub_rn(l, M), L);
                if (lp == negL && v < hit) hit = v;
            }
            #pragma unroll
            for (int off = 1; off < 64; off <<= 1) {
                int oh = __shfl_xor(hit, off, 64);
                hit = (oh < hit) ? oh : hit;
            }
            if (hit != INT_MAX) best = hit;
        }
    }
    int bi = (best == INT_MAX) ? 0 : best;

    int unfr = unf[r];
    float lp = negL;
    int itn = unfr ? bi : 0;
    int unfn = (unfr && itn != EOS) ? 1 : 0;
    if (lane == 0) { it[r] = itn; unf[r] = unfn; }
    if (lane < NS) {
        long ro = (long)r * NS + lane;
        out[ro * T_STEPS + t] = (float)itn;
        out[(long)BFULL * T_STEPS + ro * T_STEPS + t] = lp;
        out[2L * BFULL * T_STEPS + ro * T_STEPS + t] = unfr ? 1.0f : 0.0f;
    }
}

// ---------------------------------------------------------------- launch
extern "C" void kernel_launch(void* const* d_in, const int* in_sizes, int n_in,
                              void* d_out, int out_size, void* d_ws, size_t ws_size,
                              hipStream_t stream) {
    float* out = (float*)d_out;

    char* w = (char*)d_ws;
    float* fin[12];
    for (int i = 0; i < 12; ++i) {
        if (i == 1 || i == 10) { fin[i] = nullptr; continue; }   // embed/W2 read raw
        fin[i] = (float*)w;
        size_t bytes = ((size_t)in_sizes[i] * 4 + 15) & ~(size_t)15;
        w += bytes;
    }
    float*  h     = (float*) w; w += (size_t)B * H * 4;
    float*  c     = (float*) w; w += (size_t)B * H * 4;
    float*  gates = (float*) w; w += (size_t)B * 4 * H * 4;
    float*  p32   = (float*) w; w += (size_t)B * H * 4;
    float*  cm    = (float*) w; w += (size_t)B * NCHUNK * 4;
    float*  cs    = (float*) w; w += (size_t)B * NCHUNK * 4;
    int*    it    = (int*)   w; w += (size_t)B * 4;
    int*    unf   = (int*)   w; w += (size_t)B * 4;
    int*    flag  = (int*)   w; w += 16;

    k_detect<<<1, 64, 0, stream>>>((const unsigned short*)d_in[1], flag);
    for (int i = 0; i < 12; ++i) {
        if (i == 1 || i == 10) continue;
        int n = in_sizes[i];
        k_transcode<<<(n + 255) / 256, 256, 0, stream>>>(d_in[i], fin[i], n, flag);
    }

    const float* xf  = fin[0];
    const float* Wfc = fin[2];
    const float* bfc = fin[3];
    const float* Wih = fin[4];
    const float* bih = fin[5];
    const float* Whh = fin[6];
    const float* bhh = fin[7];
    const float* W1  = fin[8];
    const float* b1  = fin[9];
    const float* b2  = fin[11];

    k_init_state<<<(B + 255) / 256, 256, 0, stream>>>(it, unf);
    k_init_hc<<<B, 256, 0, stream>>>(xf, Wfc, bfc, h, c);
    for (int t = 0; t < T_STEPS; ++t) {
        k_gates<<<dim3(B / 64, 8), 256, 0, stream>>>(d_in[1], h, Wih, Whh, bih, bhh, it, gates, flag);
        k_cell_proj<<<B / 8, 256, 0, stream>>>(gates, h, c, W1, b1, p32);
        k_vchunk<<<dim3(B / 128, NCHUNK), 256, 0, stream>>>(p32, d_in[10], b2, cm, cs, flag);
        k_final<<<B, 64, 0, stream>>>(cm, cs, p32, d_in[10], b2, it, unf, out, t, flag);
    }
}

// Round 10
// 3954.555 us; speedup vs baseline: 1.5721x; 1.3166x over previous
//
#include <hip/hip_runtime.h>
#include <math.h>
#include <limits.h>

#define H 128
#define V 32000
#define CD 256
#define T_STEPS 21
#define NS 5
#define SOS 1
#define EOS 2
#define B 1024          // unique rows; reference B=5120 is 5 identical copies of each
#define BFULL 5120
#define NCHUNK 250      // V / 128

__device__ __forceinline__ float bf2f(unsigned short u) {
    return __uint_as_float(((unsigned)u) << 16);
}

// np-faithful f32 sigmoid/tanh: f64 interior, single f32 round per np op.
__device__ __forceinline__ float sig32(float x) {
    float t = (float)exp(-(double)x);
    float r = __fadd_rn(1.0f, t);
    return __fdiv_rn(1.0f, r);
}
__device__ __forceinline__ float tanh32(float x) { return (float)tanh((double)x); }

// ---------------------------------------------------------------- input dtype sniffer
__global__ void k_detect(const unsigned short* __restrict__ e, int* __restrict__ flag) {
    int i = threadIdx.x;
    unsigned short u = e[2 * i];
    int ex = (u >> 7) & 0xFF;
    bool wild = ((u & 0x7FFF) != 0) && (ex < 0x60 || ex > 0x8F);
    unsigned long long m = __ballot(wild);
    if (i == 0) *flag = (m != 0ull) ? 1 : 0;   // 1 = f32 inputs, 0 = bf16
}

// ---------------------------------------------------------------- transcode input -> f32
__global__ void k_transcode(const void* __restrict__ src, float* __restrict__ dst,
                            int n, const int* __restrict__ flag) {
    int i = blockIdx.x * blockDim.x + threadIdx.x;
    if (i >= n) return;
    if (*flag) dst[i] = ((const float*)src)[i];
    else       dst[i] = bf2f(((const unsigned short*)src)[i]);
}

// ---------------------------------------------------------------- ||W2_v||2 per vocab row (once per launch)
__global__ void k_wnorm(const void* __restrict__ W2_raw, float* __restrict__ wn,
                        const int* __restrict__ flag) {
    int v = blockIdx.x * blockDim.x + threadIdx.x;
    if (v >= V) return;
    float s = 0.f;
    if (*flag) {
        const float* w = (const float*)W2_raw + (long)v * H;
        for (int k = 0; k < H; ++k) s += w[k] * w[k];
    } else {
        const unsigned short* w = (const unsigned short*)W2_raw + (long)v * H;
        for (int k = 0; k < H; ++k) { float f = bf2f(w[k]); s += f * f; }
    }
    wn[v] = sqrtf(s);
}

// ---------------------------------------------------------------- global max ||w|| (once per launch)
__global__ __launch_bounds__(256) void k_wmax(const float* __restrict__ wn, float* __restrict__ wmax) {
    __shared__ float red[4];
    int tid = threadIdx.x;
    float m = 0.f;
    for (int i = tid; i < V; i += 256) m = fmaxf(m, wn[i]);
    #pragma unroll
    for (int off = 1; off < 64; off <<= 1) m = fmaxf(m, __shfl_xor(m, off, 64));
    if ((tid & 63) == 0) red[tid >> 6] = m;
    __syncthreads();
    if (tid == 0) *wmax = fmaxf(fmaxf(red[0], red[1]), fmaxf(red[2], red[3]));
}

// ---------------------------------------------------------------- init it/unf
__global__ void k_init_state(int* __restrict__ it, int* __restrict__ unf) {
    int i = blockIdx.x * blockDim.x + threadIdx.x;
    if (i < B) { it[i] = SOS; unf[i] = 1; }
}

// ---------------------------------------------------------------- hc = fl32(x @ W_fc.T) + b_fc
__global__ __launch_bounds__(256) void k_init_hc(
    const float* __restrict__ xf, const float* __restrict__ Wfc,
    const float* __restrict__ bfc, float* __restrict__ h, float* __restrict__ c) {
    __shared__ float xl[CD];
    int r = blockIdx.x;
    int j = threadIdx.x;
    xl[j] = xf[(long)r * CD + j];
    __syncthreads();
    const float4* w4 = (const float4*)(Wfc + (long)j * CD);
    double acc = 0.0;
    for (int k4 = 0; k4 < CD / 4; ++k4) {
        float4 w = w4[k4];
        int k = k4 * 4;
        acc += (double)xl[k]     * (double)w.x;
        acc += (double)xl[k + 1] * (double)w.y;
        acc += (double)xl[k + 2] * (double)w.z;
        acc += (double)xl[k + 3] * (double)w.w;
    }
    float hc = __fadd_rn((float)acc, bfc[j]);
    if (j < H) h[(long)r * H + j] = hc;
    else       c[(long)r * H + (j - H)] = hc;
}

// ---------------------------------------------------------------- gates (f32 np-faithful) — r5 verbatim
__global__ __launch_bounds__(256) void k_gates(
    const void* __restrict__ embed_raw, const float* __restrict__ h,
    const float* __restrict__ Wih, const float* __restrict__ Whh,
    const float* __restrict__ bih, const float* __restrict__ bhh,
    const int* __restrict__ it, float* __restrict__ gates,
    const int* __restrict__ flag) {
    __shared__ float At[16][68];
    __shared__ float Wt[16][68];
    const bool isf = (*flag != 0);
    int tid = threadIdx.x;
    int tx = tid & 15, ty = tid >> 4;
    int rb = blockIdx.x * 64, gb = blockIdx.y * 64;
    int lr = tid >> 2;
    int lq = (tid & 3) * 4;
    int arow = rb + lr;
    int grow = gb + lr;
    int tok = it[arow];
    const float*          erow_f = (const float*)embed_raw + (long)tok * H;
    const unsigned short* erow_h = (const unsigned short*)embed_raw + (long)tok * H;
    const float* hrow = h + (long)arow * H;
    const float* wi   = Wih + (long)grow * H;
    const float* wh   = Whh + (long)grow * H;
    double acc1[4][4] = {};
    double acc2[4][4] = {};
    for (int k0 = 0; k0 < 2 * H; k0 += 16) {
        int k = k0 + lq;
        float v0, v1, v2, v3;
        if (k < H) {
            if (isf) {
                float4 f = *(const float4*)(erow_f + k);
                v0 = f.x; v1 = f.y; v2 = f.z; v3 = f.w;
            } else {
                ushort4 u = *(const ushort4*)(erow_h + k);
                v0 = bf2f(u.x); v1 = bf2f(u.y); v2 = bf2f(u.z); v3 = bf2f(u.w);
            }
        } else {
            float4 f = *(const float4*)(hrow + (k - H));
            v0 = f.x; v1 = f.y; v2 = f.z; v3 = f.w;
        }
        At[lq + 0][lr] = v0; At[lq + 1][lr] = v1; At[lq + 2][lr] = v2; At[lq + 3][lr] = v3;
        float4 g;
        if (k < H) g = *(const float4*)(wi + k);
        else       g = *(const float4*)(wh + (k - H));
        Wt[lq + 0][lr] = g.x; Wt[lq + 1][lr] = g.y; Wt[lq + 2][lr] = g.z; Wt[lq + 3][lr] = g.w;
        __syncthreads();
        if (k0 < H) {
            #pragma unroll
            for (int kk = 0; kk < 16; ++kk) {
                float a[4], w[4];
                #pragma unroll
                for (int i = 0; i < 4; ++i) a[i] = At[kk][ty * 4 + i];
                #pragma unroll
                for (int j = 0; j < 4; ++j) w[j] = Wt[kk][tx * 4 + j];
                #pragma unroll
                for (int i = 0; i < 4; ++i)
                    #pragma unroll
                    for (int j = 0; j < 4; ++j)
                        acc1[i][j] += (double)a[i] * (double)w[j];
            }
        } else {
            #pragma unroll
            for (int kk = 0; kk < 16; ++kk) {
                float a[4], w[4];
                #pragma unroll
                for (int i = 0; i < 4; ++i) a[i] = At[kk][ty * 4 + i];
                #pragma unroll
                for (int j = 0; j < 4; ++j) w[j] = Wt[kk][tx * 4 + j];
                #pragma unroll
                for (int i = 0; i < 4; ++i)
                    #pragma unroll
                    for (int j = 0; j < 4; ++j)
                        acc2[i][j] += (double)a[i] * (double)w[j];
            }
        }
        __syncthreads();
    }
    #pragma unroll
    for (int i = 0; i < 4; ++i) {
        long row = rb + ty * 4 + i;
        #pragma unroll
        for (int j = 0; j < 4; ++j) {
            int g = gb + tx * 4 + j;
            float t = __fadd_rn((float)acc1[i][j], bih[g]);
            t = __fadd_rn(t, (float)acc2[i][j]);
            t = __fadd_rn(t, bhh[g]);
            gates[row * (4 * H) + g] = t;
        }
    }
}

// ---------------------------------------------------------------- LSTM cell + p-projection — r5 verbatim
__global__ __launch_bounds__(256) void k_cell_proj(
    const float* __restrict__ gates, float* __restrict__ h, float* __restrict__ c,
    const float* __restrict__ W1, const float* __restrict__ b1,
    float* __restrict__ p32) {
    __shared__ float hl[8][132];
    int tid = threadIdx.x;
    int rb = blockIdx.x * 8;
    #pragma unroll
    for (int i = 0; i < 4; ++i) {
        int lin = tid + i * 256;
        int lr = lin >> 7, j = lin & 127;
        long row = rb + lr;
        const float* g = gates + row * 512;
        float gi = g[j], gf = g[j + 128], gg = g[j + 256], go = g[j + 384];
        float cv = c[row * 128 + j];
        float si = sig32(gi);
        float sf = sig32(gf);
        float so = sig32(go);
        float tg = tanh32(gg);
        float cn = __fadd_rn(__fmul_rn(sf, cv), __fmul_rn(si, tg));
        float hn = __fmul_rn(so, tanh32(cn));
        c[row * 128 + j] = cn;
        h[row * 128 + j] = hn;
        hl[lr][j] = hn;
    }
    __syncthreads();
    int j = tid & 127;
    int rbase = (tid >> 7) * 4;
    const float4* w4 = (const float4*)(W1 + (long)j * H);
    double acc[4] = {};
    for (int k4 = 0; k4 < H / 4; ++k4) {
        float4 w = w4[k4];
        int k = k4 * 4;
        #pragma unroll
        for (int rr = 0; rr < 4; ++rr) {
            acc[rr] += (double)hl[rbase + rr][k]     * (double)w.x;
            acc[rr] += (double)hl[rbase + rr][k + 1] * (double)w.y;
            acc[rr] += (double)hl[rbase + rr][k + 2] * (double)w.z;
            acc[rr] += (double)hl[rbase + rr][k + 3] * (double)w.w;
        }
    }
    #pragma unroll
    for (int rr = 0; rr < 4; ++rr) {
        long row = rb + rbase + rr;
        p32[row * H + j] = __fadd_rn((float)acc[rr], b1[j]);
    }
}

// ---------------------------------------------------------------- f32 vocab scan (approx, rigorously bounded):
// 128 rows x 128 cols per block, f32 fmaf accumulators, same staging as r9.
// Emits per (row, chunk): approx max and f32 expf sum. Exactness restored in
// k_final via norm-bounded candidate rescue (|f32dot - f64dot| <= 130u*||p||*||w||).
__global__ __launch_bounds__(256, 3) void k_vscan32(
    const float* __restrict__ p32, const void* __restrict__ W2_raw,
    const float* __restrict__ b2, float* __restrict__ cm,
    float* __restrict__ cs, const int* __restrict__ flag) {
    __shared__ float At[16][132];
    __shared__ float Wt[16][132];
    const bool isf = (*flag != 0);
    int tid = threadIdx.x;
    int tx = tid & 15, ty = tid >> 4;
    int rb = blockIdx.x * 128;
    int cb = blockIdx.y;
    int vb = cb * 128;
    float acc[8][8] = {};
    for (int k0 = 0; k0 < H; k0 += 16) {
        #pragma unroll
        for (int i = 0; i < 2; ++i) {
            int lin = tid + i * 256;           // 0..511
            int row = lin >> 2, kq = (lin & 3) * 4;
            float4 a = *(const float4*)(p32 + (long)(rb + row) * H + k0 + kq);
            At[kq + 0][row] = a.x; At[kq + 1][row] = a.y;
            At[kq + 2][row] = a.z; At[kq + 3][row] = a.w;
            if (isf) {
                float4 g = *(const float4*)((const float*)W2_raw + (long)(vb + row) * H + k0 + kq);
                Wt[kq + 0][row] = g.x; Wt[kq + 1][row] = g.y;
                Wt[kq + 2][row] = g.z; Wt[kq + 3][row] = g.w;
            } else {
                ushort4 u = *(const ushort4*)((const unsigned short*)W2_raw + (long)(vb + row) * H + k0 + kq);
                Wt[kq + 0][row] = bf2f(u.x); Wt[kq + 1][row] = bf2f(u.y);
                Wt[kq + 2][row] = bf2f(u.z); Wt[kq + 3][row] = bf2f(u.w);
            }
        }
        __syncthreads();
        #pragma unroll
        for (int kk = 0; kk < 16; ++kk) {
            float a8[8], w8[8];
            #pragma unroll
            for (int i = 0; i < 8; ++i) a8[i] = At[kk][ty * 8 + i];
            #pragma unroll
            for (int j = 0; j < 8; ++j) w8[j] = Wt[kk][tx * 8 + j];
            #pragma unroll
            for (int i = 0; i < 8; ++i)
                #pragma unroll
                for (int j = 0; j < 8; ++j)
                    acc[i][j] = fmaf(a8[i], w8[j], acc[i][j]);
        }
        __syncthreads();
    }
    float bb[8];
    #pragma unroll
    for (int j = 0; j < 8; ++j) bb[j] = b2[vb + tx * 8 + j];
    #pragma unroll
    for (int i = 0; i < 8; ++i) {
        float mx = -__builtin_inff();
        float s = 0.f;
        #pragma unroll
        for (int j = 0; j < 8; ++j) {
            float l = acc[i][j] + bb[j];
            mx = fmaxf(mx, l);
            s += __expf(l);
        }
        #pragma unroll
        for (int off = 1; off < 16; off <<= 1) {
            mx = fmaxf(mx, __shfl_xor(mx, off, 64));
            s += __shfl_xor(s, off, 64);
        }
        if (tx == 0) {
            long row = rb + ty * 8 + i;
            cm[row * NCHUNK + cb] = mx;
            cs[row * NCHUNK + cb] = s;
        }
    }
}

// ---------------------------------------------------------------- finalize: norm-bounded candidate set, exact f64 rescue
__global__ __launch_bounds__(64) void k_final(
    const float* __restrict__ cm, const float* __restrict__ cs,
    const float* __restrict__ p32, const void* __restrict__ W2_raw,
    const float* __restrict__ b2, const float* __restrict__ wmax,
    int* __restrict__ it, int* __restrict__ unf,
    float* __restrict__ out, int t, const int* __restrict__ flag) {
    const bool isf = (*flag != 0);
    int r = blockIdx.x;
    int lane = threadIdx.x;
    const float* cmr = cm + (long)r * NCHUNK;
    const float* csr = cs + (long)r * NCHUNK;
    const float* pr = p32 + (long)r * H;

    // ||p||
    float pa = pr[lane], pb = pr[lane + 64];
    float pn2 = pa * pa + pb * pb;
    #pragma unroll
    for (int off = 1; off < 64; off <<= 1) pn2 += __shfl_xor(pn2, off, 64);
    // rigorous window: 4 * (160*2^-24) * ||p|| * max||w|| + 1e-5
    float eps = 3.8147e-5f * sqrtf(pn2) * (*wmax) + 1e-5f;

    float marr[4];
    float AM = -__builtin_inff();
    #pragma unroll
    for (int i = 0; i < 4; ++i) {
        int cc = lane + 64 * i;
        marr[i] = (cc < NCHUNK) ? cmr[cc] : -__builtin_inff();
        AM = fmaxf(AM, marr[i]);
    }
    #pragma unroll
    for (int off = 1; off < 64; off <<= 1) AM = fmaxf(AM, __shfl_xor(AM, off, 64));
    double S = 0.0;
    #pragma unroll
    for (int i = 0; i < 4; ++i) {
        int cc = lane + 64 * i;
        if (cc < NCHUNK) S += (double)csr[cc];
    }
    #pragma unroll
    for (int off = 1; off < 64; off <<= 1) S += __shfl_xor(S, off, 64);

    // pass A: exact f64-recipe max over candidate chunks -> exact global max M
    float M = -__builtin_inff();
    #pragma unroll 1
    for (int i = 0; i < 4; ++i) {
        unsigned long long mask = __ballot(marr[i] >= AM - eps);
        while (mask) {
            int b = __ffsll(mask) - 1;
            mask &= mask - 1;
            int cc = i * 64 + b;
            #pragma unroll
            for (int q = 0; q < 2; ++q) {
                int v = cc * 128 + q * 64 + lane;
                double acc = 0.0;
                if (isf) {
                    const float* wv = (const float*)W2_raw + (long)v * H;
                    for (int k = 0; k < H; ++k) acc += (double)pr[k] * (double)wv[k];
                } else {
                    const unsigned short* wv = (const unsigned short*)W2_raw + (long)v * H;
                    for (int k = 0; k < H; ++k) acc += (double)pr[k] * (double)bf2f(wv[k]);
                }
                float l = __fadd_rn((float)acc, b2[v]);
                M = fmaxf(M, l);
            }
        }
    }
    #pragma unroll
    for (int off = 1; off < 64; off <<= 1) M = fmaxf(M, __shfl_xor(M, off, 64));

    float L = (float)(log(S) - (double)M);
    float negL = __fsub_rn(0.0f, L);

    // pass B: first v (ascending) whose f32 logprob equals the max logprob -L
    int best = INT_MAX;
    #pragma unroll 1
    for (int i = 0; i < 4 && best == INT_MAX; ++i) {
        unsigned long long mask = __ballot(marr[i] >= AM - eps);
        while (mask && best == INT_MAX) {
            int b = __ffsll(mask) - 1;
            mask &= mask - 1;
            int cc = i * 64 + b;
            int hit = INT_MAX;
            #pragma unroll
            for (int q = 0; q < 2; ++q) {
                int v = cc * 128 + q * 64 + lane;
                double acc = 0.0;
                if (isf) {
                    const float* wv = (const float*)W2_raw + (long)v * H;
                    for (int k = 0; k < H; ++k) acc += (double)pr[k] * (double)wv[k];
                } else {
                    const unsigned short* wv = (const unsigned short*)W2_raw + (long)v * H;
                    for (int k = 0; k < H; ++k) acc += (double)pr[k] * (double)bf2f(wv[k]);
                }
                float l  = __fadd_rn((float)acc, b2[v]);
                float lp = __fsub_rn(__fsub_rn(l, M), L);
                if (lp == negL && v < hit) hit = v;
            }
            #pragma unroll
            for (int off = 1; off < 64; off <<= 1) {
                int oh = __shfl_xor(hit, off, 64);
                hit = (oh < hit) ? oh : hit;
            }
            if (hit != INT_MAX) best = hit;
        }
    }
    int bi = (best == INT_MAX) ? 0 : best;

    int unfr = unf[r];
    float lp = negL;
    int itn = unfr ? bi : 0;
    int unfn = (unfr && itn != EOS) ? 1 : 0;
    if (lane == 0) { it[r] = itn; unf[r] = unfn; }
    if (lane < NS) {
        long ro = (long)r * NS + lane;
        out[ro * T_STEPS + t] = (float)itn;
        out[(long)BFULL * T_STEPS + ro * T_STEPS + t] = lp;
        out[2L * BFULL * T_STEPS + ro * T_STEPS + t] = unfr ? 1.0f : 0.0f;
    }
}

// ---------------------------------------------------------------- launch
extern "C" void kernel_launch(void* const* d_in, const int* in_sizes, int n_in,
                              void* d_out, int out_size, void* d_ws, size_t ws_size,
                              hipStream_t stream) {
    float* out = (float*)d_out;

    char* w = (char*)d_ws;
    float* fin[12];
    for (int i = 0; i < 12; ++i) {
        if (i == 1 || i == 10) { fin[i] = nullptr; continue; }   // embed/W2 read raw
        fin[i] = (float*)w;
        size_t bytes = ((size_t)in_sizes[i] * 4 + 15) & ~(size_t)15;
        w += bytes;
    }
    float*  h     = (float*) w; w += (size_t)B * H * 4;
    float*  c     = (float*) w; w += (size_t)B * H * 4;
    float*  gates = (float*) w; w += (size_t)B * 4 * H * 4;
    float*  p32   = (float*) w; w += (size_t)B * H * 4;
    float*  cm    = (float*) w; w += (size_t)B * NCHUNK * 4;
    float*  cs    = (float*) w; w += (size_t)B * NCHUNK * 4;
    float*  wn    = (float*) w; w += (size_t)V * 4;
    float*  wmax  = (float*) w; w += 16;
    int*    it    = (int*)   w; w += (size_t)B * 4;
    int*    unf   = (int*)   w; w += (size_t)B * 4;
    int*    flag  = (int*)   w; w += 16;

    k_detect<<<1, 64, 0, stream>>>((const unsigned short*)d_in[1], flag);
    for (int i = 0; i < 12; ++i) {
        if (i == 1 || i == 10) continue;
        int n = in_sizes[i];
        k_transcode<<<(n + 255) / 256, 256, 0, stream>>>(d_in[i], fin[i], n, flag);
    }
    k_wnorm<<<(V + 255) / 256, 256, 0, stream>>>(d_in[10], wn, flag);
    k_wmax<<<1, 256, 0, stream>>>(wn, wmax);

    const float* xf  = fin[0];
    const float* Wfc = fin[2];
    const float* bfc = fin[3];
    const float* Wih = fin[4];
    const float* bih = fin[5];
    const float* Whh = fin[6];
    const float* bhh = fin[7];
    const float* W1  = fin[8];
    const float* b1  = fin[9];
    const float* b2  = fin[11];

    k_init_state<<<(B + 255) / 256, 256, 0, stream>>>(it, unf);
    k_init_hc<<<B, 256, 0, stream>>>(xf, Wfc, bfc, h, c);
    for (int t = 0; t < T_STEPS; ++t) {
        k_gates<<<dim3(B / 64, 8), 256, 0, stream>>>(d_in[1], h, Wih, Whh, bih, bhh, it, gates, flag);
        k_cell_proj<<<B / 8, 256, 0, stream>>>(gates, h, c, W1, b1, p32);
        k_vscan32<<<dim3(B / 128, NCHUNK), 256, 0, stream>>>(p32, d_in[10], b2, cm, cs, flag);
        k_final<<<B, 64, 0, stream>>>(cm, cs, p32, d_in[10], b2, wmax, it, unf, out, t, flag);
    }
}